// Round 1
// 889.159 us; speedup vs baseline: 1.1822x; 1.1822x over previous
//
#include <hip/hip_runtime.h>
#include <hip/hip_bf16.h>

typedef __attribute__((ext_vector_type(8))) short      short8;
typedef __attribute__((ext_vector_type(4))) float      floatx4;
typedef unsigned long long u64;
typedef unsigned short     u16;

#define DI __device__ __forceinline__

constexpr int BB = 2, HH = 16, SS = 2048, DD = 64;
constexpr int TK  = 64;               // kv per tile
constexpr int NKT = SS / TK;          // 32 kv tiles
constexpr int PW  = 68;               // f32 LDS pitch: 272B rows (16B aligned, 2-way banks on write)

// ---- workspace layout (bytes) ----
constexpr size_t NELEM  = (size_t)BB * HH * SS * DD;    // 4 Mi elements
constexpr size_t OFF_VT = NELEM * 2;                    // Kb bf16: [0, 8MB)
constexpr size_t OFF_MB = OFF_VT + NELEM * 2;           // Vt bf16: [8MB, 16MB)
constexpr size_t NWORDS = (size_t)BB * SS * (SS / 64);  // 131072 u64 mask words

DI u16 f2bfu(float f) {
    __hip_bfloat16 h = __float2bfloat16(f);
    return __builtin_bit_cast(u16, h);
}

DI short8 pack8(floatx4 a, floatx4 b) {
    short8 r;
    r[0] = (short)f2bfu(a[0]); r[1] = (short)f2bfu(a[1]);
    r[2] = (short)f2bfu(a[2]); r[3] = (short)f2bfu(a[3]);
    r[4] = (short)f2bfu(b[0]); r[5] = (short)f2bfu(b[1]);
    r[6] = (short)f2bfu(b[2]); r[7] = (short)f2bfu(b[3]);
    return r;
}

// load 8 f32, scale, pack to bf16 MFMA half-fragment
DI short8 cvt8s(const float* __restrict__ p, float s) {
    floatx4 a = *(const floatx4*)p;
    floatx4 b = *(const floatx4*)(p + 4);
    a *= s; b *= s;
    return pack8(a, b);
}

// =================== prep: K->bf16, V->bf16 transposed, mask->bits ===================
constexpr int KBLK = 2048;   // 2048 blocks * 256 thr * 8 elem = 4Mi K elements
constexpr int VBLK = 1024;   // 32 kv-tiles * 32 heads
constexpr int MBLK = 4096;   // 4096 blocks * 4 waves * 8 words = 131072 words

__global__ __launch_bounds__(256)
void prep_kernel(const float* __restrict__ K, const float* __restrict__ V,
                 const int* __restrict__ mask,
                 u16* __restrict__ Kb, u16* __restrict__ Vt, u64* __restrict__ Mb)
{
    const int bx = (int)blockIdx.x, tid = (int)threadIdx.x;
    if (bx < KBLK) {
        // K f32 -> bf16, same layout [bh][s][d]
        size_t i = ((size_t)bx * 256 + tid) * 8;
        floatx4 a = *(const floatx4*)(K + i);
        floatx4 b = *(const floatx4*)(K + i + 4);
        *(short8*)(Kb + i) = pack8(a, b);
    } else if (bx < KBLK + VBLK) {
        // V [bh][s][d] f32 -> Vt [bh][d][s] bf16, 64x64 tile via LDS
        __shared__ __align__(16) u16 T[DD * 72];
        const int idx = bx - KBLK;
        const int bh = idx >> 5, kt = idx & 31;
        const int kvr = tid >> 2, d0 = (tid & 3) * 16;
        const float* vp = V + ((size_t)bh * SS + kt * 64 + kvr) * DD + d0;
        floatx4 v0 = *(const floatx4*)vp;
        floatx4 v1 = *(const floatx4*)(vp + 4);
        floatx4 v2 = *(const floatx4*)(vp + 8);
        floatx4 v3 = *(const floatx4*)(vp + 12);
#pragma unroll
        for (int i = 0; i < 4; ++i) T[(d0 + i)      * 72 + kvr] = f2bfu(v0[i]);
#pragma unroll
        for (int i = 0; i < 4; ++i) T[(d0 + 4 + i)  * 72 + kvr] = f2bfu(v1[i]);
#pragma unroll
        for (int i = 0; i < 4; ++i) T[(d0 + 8 + i)  * 72 + kvr] = f2bfu(v2[i]);
#pragma unroll
        for (int i = 0; i < 4; ++i) T[(d0 + 12 + i) * 72 + kvr] = f2bfu(v3[i]);
        __syncthreads();
        const int d = tid >> 2, seg = (tid & 3) * 16;
        short8 s0 = *(const short8*)&T[d * 72 + seg];
        short8 s1 = *(const short8*)&T[d * 72 + seg + 8];
        u16* op = Vt + ((size_t)bh * DD + d) * SS + kt * 64 + seg;
        *(short8*)op       = s0;
        *(short8*)(op + 8) = s1;
    } else {
        // mask int32 [b][s][s] -> bit-packed u64 words [b][s][s/64] via ballot
        const int mc = bx - (KBLK + VBLK);
        const int wv = tid >> 6, lane = tid & 63;
        const size_t gw = (size_t)mc * 4 + wv;
#pragma unroll
        for (int it = 0; it < 8; ++it) {
            size_t word = gw * 8 + it;                  // 0 .. 131071
            int b   = (int)(word >> 16);                // 65536 words per batch
            int rem = (int)(word & 65535);
            int q = rem >> 5, wj = rem & 31;
            int v = mask[((size_t)b * SS + q) * SS + wj * 64 + lane];
            u64 bal = __ballot(v != 0);
            if (lane == 0) Mb[word] = bal;
        }
    }
}

// =================== main: 1 wave per block, 16 q-rows, barrier-free ===================
__global__ __launch_bounds__(64, 4)
void sdpa_main(const float* __restrict__ Q,
               const u16*   __restrict__ Kb,
               const u16*   __restrict__ Vt,
               const u64*   __restrict__ Mb,
               float*       __restrict__ out_ctx,
               float*       __restrict__ out_w)
{
    __shared__ __align__(16) float Pw[16 * PW];   // wave-private f32 P tile (16 rows x 64 kv)

    const int lane = (int)threadIdx.x;
    const int quad = lane >> 4;
    const int col  = lane & 15;

    const int bh = (int)blockIdx.y;               // b*16 + h
    const int b  = bh >> 4;
    const int q0 = (int)blockIdx.x * 16;          // this wave's 16 q-rows

    const size_t head = (size_t)bh * SS * DD;
    const u16* Kh = Kb + head;                    // [kv][d] bf16
    const u16* Vh = Vt + head;                    // [d][kv] bf16
    const u64* Mh = Mb + ((size_t)b * SS + q0) * (SS / 64);
    float*     Wh = out_w + (size_t)bh * SS * SS;

    // Q A-fragments, pre-scaled by 1/sqrt(64)=0.125 (exact pow2: bit-identical scores)
    short8 aQ0, aQ1;
    {
        const float* qp = Q + head + (size_t)(q0 + col) * DD + quad * 8;
        aQ0 = cvt8s(qp, 0.125f);
        aQ1 = cvt8s(qp + 32, 0.125f);
    }

    // ---------------- pass 1: online (m, l) ----------------
    float mrow[4], lrow[4];
#pragma unroll
    for (int r = 0; r < 4; ++r) { mrow[r] = -__builtin_inff(); lrow[r] = 0.f; }

    for (int kt = 0; kt < NKT; ++kt) {
        const int kv0 = kt * TK;
        floatx4 acc[4];
#pragma unroll
        for (int nt = 0; nt < 4; ++nt) {
            const u16* kp = Kh + (size_t)(kv0 + nt * 16 + col) * DD + quad * 8;
            short8 b0 = *(const short8*)kp;
            short8 b1 = *(const short8*)(kp + 32);
            floatx4 a = {0.f, 0.f, 0.f, 0.f};
            a = __builtin_amdgcn_mfma_f32_16x16x32_bf16(aQ0, b0, a, 0, 0, 0);
            a = __builtin_amdgcn_mfma_f32_16x16x32_bf16(aQ1, b1, a, 0, 0, 0);
            acc[nt] = a;
        }
#pragma unroll
        for (int r = 0; r < 4; ++r) {
            const int rloc = quad * 4 + r;
            const u64 mw = Mh[(size_t)rloc * (SS / 64) + kt];
            float s[4];
#pragma unroll
            for (int nt = 0; nt < 4; ++nt) {
                unsigned mnt = (unsigned)(mw >> (nt * 16));
                s[nt] = ((mnt >> col) & 1u) ? acc[nt][r] : -1e9f;
            }
            float lm = fmaxf(fmaxf(s[0], s[1]), fmaxf(s[2], s[3]));
            float mn = fmaxf(mrow[r], lm);
            float p  = __expf(s[0] - mn) + __expf(s[1] - mn) + __expf(s[2] - mn) + __expf(s[3] - mn);
            lrow[r]  = lrow[r] * __expf(mrow[r] - mn) + p;
            mrow[r]  = mn;
        }
    }
    // merge (m,l) across the 16 lanes sharing rows quad*4+r
#pragma unroll
    for (int r = 0; r < 4; ++r) {
#pragma unroll
        for (int off = 1; off < 16; off <<= 1) {
            float mo = __shfl_xor(mrow[r], off);
            float lo = __shfl_xor(lrow[r], off);
            float mn = fmaxf(mrow[r], mo);
            lrow[r] = lrow[r] * __expf(mrow[r] - mn) + lo * __expf(mo - mn);
            mrow[r] = mn;
        }
    }
    float rl[4];
#pragma unroll
    for (int r = 0; r < 4; ++r) rl[r] = 1.0f / lrow[r];

    // ---------------- pass 2: recompute, write weights, fuse PV ----------------
    floatx4 ctx[4];
#pragma unroll
    for (int nt = 0; nt < 4; ++nt) ctx[nt] = floatx4{0.f, 0.f, 0.f, 0.f};

    for (int kt = 0; kt < NKT; ++kt) {
        const int kv0 = kt * TK;

        floatx4 acc[4];
#pragma unroll
        for (int nt = 0; nt < 4; ++nt) {
            const u16* kp = Kh + (size_t)(kv0 + nt * 16 + col) * DD + quad * 8;
            short8 b0 = *(const short8*)kp;
            short8 b1 = *(const short8*)(kp + 32);
            floatx4 a = {0.f, 0.f, 0.f, 0.f};
            a = __builtin_amdgcn_mfma_f32_16x16x32_bf16(aQ0, b0, a, 0, 0, 0);
            a = __builtin_amdgcn_mfma_f32_16x16x32_bf16(aQ1, b1, a, 0, 0, 0);
            acc[nt] = a;
        }

        // normalized weights -> wave-private LDS (f32)
#pragma unroll
        for (int r = 0; r < 4; ++r) {
            const int rloc = quad * 4 + r;
            const u64 mw = Mh[(size_t)rloc * (SS / 64) + kt];
#pragma unroll
            for (int nt = 0; nt < 4; ++nt) {
                unsigned mnt = (unsigned)(mw >> (nt * 16));
                float sv = ((mnt >> col) & 1u) ? acc[nt][r] : -1e9f;
                Pw[rloc * PW + nt * 16 + col] = __expf(sv - mrow[r]) * rl[r];
            }
        }
        __syncthreads();   // 1-wave block: just an LDS drain, no inter-wave stall

        // P A-fragments (f32 LDS -> bf16)
        floatx4 pf0 = *(const floatx4*)&Pw[col * PW + quad * 8];
        floatx4 pf1 = *(const floatx4*)&Pw[col * PW + quad * 8 + 4];
        floatx4 pf2 = *(const floatx4*)&Pw[col * PW + 32 + quad * 8];
        floatx4 pf3 = *(const floatx4*)&Pw[col * PW + 32 + quad * 8 + 4];
        short8 pA0 = pack8(pf0, pf1);
        short8 pA1 = pack8(pf2, pf3);

        // coalesced 256B nontemporal weight stores (bypass cache pollution)
#pragma unroll
        for (int i = 0; i < 4; ++i) {
            const int wr = (lane >> 4) + i * 4;
            const int c4 = (lane & 15) * 4;
            floatx4 wv = *(const floatx4*)&Pw[wr * PW + c4];
            __builtin_nontemporal_store(wv, (floatx4*)(Wh + (size_t)(q0 + wr) * SS + kv0 + c4));
        }

        // PV: B-fragments straight from global V^T (L2-hot, no staging)
#pragma unroll
        for (int nt = 0; nt < 4; ++nt) {
            const u16* vp = Vh + (size_t)(nt * 16 + col) * SS + kv0 + quad * 8;
            short8 vB0 = *(const short8*)vp;
            short8 vB1 = *(const short8*)(vp + 32);
            ctx[nt] = __builtin_amdgcn_mfma_f32_16x16x32_bf16(pA0, vB0, ctx[nt], 0, 0, 0);
            ctx[nt] = __builtin_amdgcn_mfma_f32_16x16x32_bf16(pA1, vB1, ctx[nt], 0, 0, 0);
        }
        __syncthreads();   // protect LDS reads from next tile's writes
    }

    // ---- context epilogue ----
#pragma unroll
    for (int nt = 0; nt < 4; ++nt) {
#pragma unroll
        for (int r = 0; r < 4; ++r) {
            const int q = q0 + quad * 4 + r;
            __builtin_nontemporal_store(ctx[nt][r],
                out_ctx + head + (size_t)q * DD + nt * 16 + col);
        }
    }
}

extern "C" void kernel_launch(void* const* d_in, const int* in_sizes, int n_in,
                              void* d_out, int out_size, void* d_ws, size_t ws_size,
                              hipStream_t stream) {
    const float* Q = (const float*)d_in[0];
    const float* K = (const float*)d_in[1];
    const float* V = (const float*)d_in[2];
    const int* mask = (const int*)d_in[3];

    float* out     = (float*)d_out;
    float* out_ctx = out;                               // [B,H,S,D]
    float* out_w   = out + (size_t)BB * HH * SS * DD;   // [B,H,S,S]

    // workspace: Kb bf16 (8MB) | Vt bf16 (8MB) | mask bits (1MB)  — 17MB total
    u16* Kb = (u16*)d_ws;
    u16* Vt = (u16*)((char*)d_ws + OFF_VT);
    u64* Mb = (u64*)((char*)d_ws + OFF_MB);
    (void)ws_size;

    hipLaunchKernelGGL(prep_kernel, dim3(KBLK + VBLK + MBLK), dim3(256), 0, stream,
                       K, V, mask, Kb, Vt, Mb);
    hipLaunchKernelGGL(sdpa_main, dim3(SS / 16, BB * HH), dim3(64), 0, stream,
                       Q, Kb, Vt, Mb, out_ctx, out_w);
}